// Round 10
// baseline (2012.385 us; speedup 1.0000x reference)
//
#include <hip/hip_runtime.h>
#include <math.h>

// B=4, H=256, W=256, 100 iters. Closed-form update (3-pt GH quadrature is
// exact for these degree<=4 integrands; log/NDC terms cancel):
//   dmu  = 2*uw1*mu + uw2*y + sum_edges ew*mu_nb
//   dsg  = 2*uw1*sg + sum_edges ew*rou_edge*sg_nb
//   drou = ew*sg_self*sg_nb        (per owned edge)
// Round 10: ONE persistent kernel, 10 phases of T=10 temporally-blocked
// Jacobi iterations (52x52 halo tile -> 32x32 interior, r8's known-best
// inner loop), separated by a hand-rolled grid barrier (monotone counter,
// device-scope atomics + __threadfence; cross-XCD exchange correctness of
// this fence pattern was proven by r7's coop run, absmax 0.25).
// Co-residency: 256 blocks x 1024 thr, 88 KB LDS => exactly 1 block/CU on
// 256 CUs. Registers hold st/v/k1/k2 across ALL phases: per phase only
// interior st/v publish (8.4 MB) + halo st/v re-read (13.8 MB) touch global
// vs 41.6 MB/launch for the multi-launch version, and 12 launches -> 2.
// Single st/v planes: each px is interior to exactly one tile (writer);
// halo readers read it only after the barrier. No cooperative API (r3/r7:
// fails under graph capture).
#define NPIX  262144
#define ITERS 100
#define T     10
#define NPH   10           // ITERS / T
#define TILE  52           // 32 + 2*T
#define TS    53           // padded LDS row stride (float4 units) — r8 fix
#define NRG   13           // rowgroups of 4 rows: 13*4 = 52 exact
#define ACTIVE (TILE*NRG)  // 676 active threads of 1024
#define NBLK  256

__device__ __forceinline__ float clampf(float x, float lo, float hi) {
    return fminf(fmaxf(x, lo), hi);
}

// grid barrier: monotone counter, one arrival per block.
// release: every thread fences its stores, block-syncs, then thread 0
// publishes the arrival. acquire: thread 0 spins (agent-scope acquire
// loads), block-syncs, then every thread fences before reading.
__device__ __forceinline__ void gbar(unsigned int* ctr, unsigned int target) {
    __threadfence();
    __syncthreads();
    if (threadIdx.x == 0) {
        __hip_atomic_fetch_add(ctr, 1u, __ATOMIC_RELEASE,
                               __HIP_MEMORY_SCOPE_AGENT);
        while (__hip_atomic_load(ctr, __ATOMIC_ACQUIRE,
                                 __HIP_MEMORY_SCOPE_AGENT) < target)
            __builtin_amdgcn_s_sleep(8);
    }
    __syncthreads();
    __threadfence();
}

// State float4 {mu, sigma, rou0(down-edge), rou1(right-edge)}.
__global__ __launch_bounds__(1024, 4) void osi_persist(
    const float*  __restrict__ y,
    const float2* __restrict__ ew,
    const float2* __restrict__ uw,
    unsigned int* __restrict__ sync,   // [0]=barrier ctr, [1]=gmax enc; memset 0
    float4* __restrict__ stP,
    float4* __restrict__ vP,
    float* __restrict__ out)
{
    __shared__ float4 buf[2][TILE*TS];   // 88.3 KB -> 1 block/CU

    int tid = threadIdx.x;
    int rg  = tid / TILE;
    int col = tid - rg*TILE;
    bool act = (tid < ACTIVE);
    int bz = blockIdx.z;
    int h0 = blockIdx.y * 32;
    int w0 = blockIdx.x * 32;
    int w  = (w0 + col - T) & 255;
    bool cin = (col >= T) && (col < T+32);

    float4 st[4], v[4], k1[4];
    float2 k2[4];
    int    gidx[4];
    float  yv4[4];
    bool   inter[4];

    // ---- one-time load of invariants ----
    float m = -INFINITY;
    if (act) {
#pragma unroll
        for (int k = 0; k < 4; ++k) {
            int r = 4*rg + k;
            int h = (h0 + r - T) & 255;
            int g = (bz << 16) | (h << 8) | w;
            gidx[k] = g;
            float2 e = ew[g];
            float2 u = uw[g];
            float yv = y[g];
            yv4[k] = yv;
            k1[k] = make_float4(2.f*u.x, u.y*yv, e.x, e.y);
            m = fmaxf(m, fmaxf(e.x, e.y));
            inter[k] = cin && (r >= T) && (r < T+32);
        }
    }
    // one-time k2 derivation via LDS staging (buf[1], overwritten by iter 0)
    float2* ews = (float2*)&buf[1][0];
    if (act) {
#pragma unroll
        for (int k = 0; k < 4; ++k)
            ews[(4*rg + k)*TS + col] = make_float2(k1[k].z, k1[k].w);
    }
    __syncthreads();
    int cl = (col == 0)      ? 0      : col-1;
    int cr = (col == TILE-1) ? TILE-1 : col+1;
    if (act) {
#pragma unroll
        for (int k = 0; k < 4; ++k) {
            int r  = 4*rg + k;
            int ru = (r == 0) ? 0 : r-1;
            k2[k] = make_float2(ews[ru*TS + col].x, ews[r*TS + cl].y);
        }
    }

    // ---- global max(ew) (barrier #1) ----
#pragma unroll
    for (int off = 32; off > 0; off >>= 1)
        m = fmaxf(m, __shfl_down(m, off, 64));
    if ((tid & 63) == 0) {
        unsigned u = __float_as_uint(m);
        unsigned key = (u & 0x80000000u) ? ~u : (u | 0x80000000u);
        atomicMax(&sync[1], key);
    }
    gbar(&sync[0], NBLK);

    // ---- init state in registers ----
    {
        unsigned key = __hip_atomic_load(&sync[1], __ATOMIC_RELAXED,
                                         __HIP_MEMORY_SCOPE_AGENT);
        unsigned u = (key & 0x80000000u) ? (key ^ 0x80000000u) : ~key;
        float gmax = __uint_as_float(u);
        float inv_denom = 1.f / (gmax*1.01f + 1.f);   // one-time, IEEE div
        if (act) {
#pragma unroll
            for (int k = 0; k < 4; ++k) {
                st[k] = make_float4(yv4[k], 1.f,
                                    k1[k].z*inv_denom, k1[k].w*inv_denom);
                v[k]  = make_float4(0.f, 0.f, 0.f, 0.f);
            }
        }
    }

    // ---- 10 phases of T=10 fused Jacobi iterations ----
    unsigned int barno = 2;
#pragma unroll 1
    for (int p = 0; p < NPH; ++p) {
        if (act) {
#pragma unroll
            for (int k = 0; k < 4; ++k)
                buf[0][(4*rg + k)*TS + col] = st[k];
        }
        __syncthreads();

        // r8 inner loop (known-best): dbuf LDS, 1 barrier/iter
#pragma unroll 1
        for (int s = 0; s < T; ++s) {
            const float4* __restrict__ cur = buf[s & 1];
            float4*       __restrict__ nxt = buf[(s & 1) ^ 1];
            if (act) {
                int r0 = 4*rg;
                float4 ns[4];
                float4 up0 = cur[((rg == 0) ? 0 : (r0-1))*TS + col];
                float4 dn3 = cur[((rg == NRG-1) ? (TILE-1) : (r0+4))*TS + col];
#pragma unroll
                for (int k = 0; k < 4; ++k) {
                    int r = r0 + k;
                    float4 lf = cur[r*TS + cl];
                    float4 rt = cur[r*TS + cr];
                    float4 up = (k == 0) ? up0 : st[k-1];
                    float4 dn = (k == 3) ? dn3 : st[k+1];
                    float4 S  = st[k];
                    float4 K  = k1[k];
                    float2 K2 = k2[k];
                    float dmu = K.x*S.x + K.y + K.z*dn.x + K.w*rt.x
                              + K2.x*up.x + K2.y*lf.x;
                    float dsg = K.x*S.y + K.z*S.z*dn.y + K.w*S.w*rt.y
                              + K2.x*up.z*up.y + K2.y*lf.w*lf.y;
                    float dr0 = K.z*S.y*dn.y;
                    float dr1 = K.w*S.y*rt.y;
                    float4 V = v[k];
                    V.x = 0.7f*V.x + 0.01f*dmu;
                    V.y = 0.7f*V.y + 0.01f*dsg;
                    V.z = 0.7f*V.z + 0.01f*dr0;
                    V.w = 0.7f*V.w + 0.01f*dr1;
                    v[k] = V;
                    float4 o;
                    o.x = clampf(S.x + V.x, 0.f, 63.f);
                    o.y = clampf(S.y + V.y, 0.001f, 50.f);
                    o.z = clampf(S.z + V.z, -0.99f, 0.99f);
                    o.w = clampf(S.w + V.w, -0.99f, 0.99f);
                    ns[k] = o;
                }
#pragma unroll
                for (int k = 0; k < 4; ++k) {
                    st[k] = ns[k];
                    nxt[(4*rg + k)*TS + col] = ns[k];
                }
            }
            __syncthreads();
        }

        if (p < NPH-1) {
            // publish interior, grid barrier, refresh halo
            if (act) {
#pragma unroll
                for (int k = 0; k < 4; ++k) {
                    if (inter[k]) {
                        stP[gidx[k]] = st[k];
                        vP[gidx[k]]  = v[k];
                    }
                }
            }
            gbar(&sync[0], barno * NBLK);
            ++barno;
            if (act) {
#pragma unroll
                for (int k = 0; k < 4; ++k) {
                    if (!inter[k]) {
                        st[k] = stP[gidx[k]];
                        v[k]  = vP[gidx[k]];
                    }
                }
            }
        } else {
            // final phase: interior mu -> output
            if (act) {
#pragma unroll
                for (int k = 0; k < 4; ++k)
                    if (inter[k]) out[gidx[k]] = st[k].x;
            }
        }
    }
}

extern "C" void kernel_launch(void* const* d_in, const int* in_sizes, int n_in,
                              void* d_out, int out_size, void* d_ws, size_t ws_size,
                              hipStream_t stream) {
    const float*  y  = (const float*)d_in[0];
    const float2* ew = (const float2*)d_in[1];
    const float2* uw = (const float2*)d_in[2];
    float* out = (float*)d_out;

    // workspace: stP, vP (float4 planes, 8.4 MB) + sync[2]
    float4* stP = (float4*)d_ws;
    float4* vP  = stP + NPIX;
    unsigned int* sync = (unsigned int*)(vP + NPIX);

    hipMemsetAsync(sync, 0, 2*sizeof(unsigned int), stream);
    hipLaunchKernelGGL(osi_persist, dim3(8, 8, 4), dim3(1024), 0, stream,
                       y, ew, uw, sync, stP, vP, out);
}

// Round 11
// 490.610 us; speedup vs baseline: 4.1018x; 4.1018x over previous
//
#include <hip/hip_runtime.h>
#include <math.h>

// B=4, H=256, W=256, 100 iters. Closed-form update (3-pt GH quadrature is
// exact for these degree<=4 integrands; log/NDC terms cancel):
//   dmu  = 2*uw1*mu + uw2*y + sum_edges ew*mu_nb
//   dsg  = 2*uw1*sg + sum_edges ew*rou_edge*sg_nb
//   drou = ew*sg_self*sg_nb        (per owned edge)
// ONE persistent kernel, 10 phases of T=10 temporally-blocked Jacobi
// iterations (52x52 halo tile -> 32x32 interior, r8 inner loop), separated
// by a hand-rolled grid barrier.
// Round 11 fix (r10 post-mortem): r10's barrier fenced on ALL 1024 threads
// and ACQUIRE-polled — each agent-scope fence on gfx950 = buffer_wbl2 /
// buffer_inv (full per-XCD L2 writeback/invalidate), so 16 waves x 2 fences
// x 10 phases per CU pushed the whole exchange to HBM (WRITE_SIZE 97 MB,
// ~190 us/phase). Now: __syncthreads drains block stores to L2 (L1 is
// write-through, vmcnt(0) precedes s_barrier); ONLY thread 0 does the
// RELEASE RMW (one wbl2), RELAXED spin (no invalidate per poll), then ONE
// ACQUIRE fence (one invl1/invl2 — 1 block/CU, so it covers the block's L1).
// Logical semantics identical to r10 (absmax 0.25); ~32x fewer cache flushes.
#define NPIX  262144
#define ITERS 100
#define T     10
#define NPH   10           // ITERS / T
#define TILE  52           // 32 + 2*T
#define TS    53           // padded LDS row stride (float4 units) — r8 fix
#define NRG   13           // rowgroups of 4 rows: 13*4 = 52 exact
#define ACTIVE (TILE*NRG)  // 676 active threads of 1024
#define NBLK  256

__device__ __forceinline__ float clampf(float x, float lo, float hi) {
    return fminf(fmaxf(x, lo), hi);
}

// grid barrier: monotone counter, one arrival per block, thread-0-only
// fencing (see header comment).
__device__ __forceinline__ void gbar(unsigned int* ctr, unsigned int target) {
    __syncthreads();   // drains all block mem ops (vmcnt(0) before s_barrier)
    if (threadIdx.x == 0) {
        __hip_atomic_fetch_add(ctr, 1u, __ATOMIC_RELEASE,
                               __HIP_MEMORY_SCOPE_AGENT);
        while (__hip_atomic_load(ctr, __ATOMIC_RELAXED,
                                 __HIP_MEMORY_SCOPE_AGENT) < target)
            __builtin_amdgcn_s_sleep(2);
        __builtin_amdgcn_fence(__ATOMIC_ACQUIRE, "agent");  // one invalidate
    }
    __syncthreads();
}

// State float4 {mu, sigma, rou0(down-edge), rou1(right-edge)}.
__global__ __launch_bounds__(1024, 4) void osi_persist(
    const float*  __restrict__ y,
    const float2* __restrict__ ew,
    const float2* __restrict__ uw,
    unsigned int* __restrict__ sync,   // [0]=barrier ctr, [1]=gmax enc; memset 0
    float4* __restrict__ stP,
    float4* __restrict__ vP,
    float* __restrict__ out)
{
    __shared__ float4 buf[2][TILE*TS];   // 88.3 KB -> 1 block/CU

    int tid = threadIdx.x;
    int rg  = tid / TILE;
    int col = tid - rg*TILE;
    bool act = (tid < ACTIVE);
    int bz = blockIdx.z;
    int h0 = blockIdx.y * 32;
    int w0 = blockIdx.x * 32;
    int w  = (w0 + col - T) & 255;
    bool cin = (col >= T) && (col < T+32);

    float4 st[4], v[4], k1[4];
    float2 k2[4];
    int    gidx[4];
    float  yv4[4];
    bool   inter[4];

    // ---- one-time load of invariants ----
    float m = -INFINITY;
    if (act) {
#pragma unroll
        for (int k = 0; k < 4; ++k) {
            int r = 4*rg + k;
            int h = (h0 + r - T) & 255;
            int g = (bz << 16) | (h << 8) | w;
            gidx[k] = g;
            float2 e = ew[g];
            float2 u = uw[g];
            float yv = y[g];
            yv4[k] = yv;
            k1[k] = make_float4(2.f*u.x, u.y*yv, e.x, e.y);
            m = fmaxf(m, fmaxf(e.x, e.y));
            inter[k] = cin && (r >= T) && (r < T+32);
        }
    }
    // one-time k2 derivation via LDS staging (buf[1], overwritten by iter 0)
    float2* ews = (float2*)&buf[1][0];
    if (act) {
#pragma unroll
        for (int k = 0; k < 4; ++k)
            ews[(4*rg + k)*TS + col] = make_float2(k1[k].z, k1[k].w);
    }
    __syncthreads();
    int cl = (col == 0)      ? 0      : col-1;
    int cr = (col == TILE-1) ? TILE-1 : col+1;
    if (act) {
#pragma unroll
        for (int k = 0; k < 4; ++k) {
            int r  = 4*rg + k;
            int ru = (r == 0) ? 0 : r-1;
            k2[k] = make_float2(ews[ru*TS + col].x, ews[r*TS + cl].y);
        }
    }

    // ---- global max(ew) (barrier #1) ----
#pragma unroll
    for (int off = 32; off > 0; off >>= 1)
        m = fmaxf(m, __shfl_down(m, off, 64));
    if ((tid & 63) == 0) {
        unsigned u = __float_as_uint(m);
        unsigned key = (u & 0x80000000u) ? ~u : (u | 0x80000000u);
        atomicMax(&sync[1], key);
    }
    gbar(&sync[0], NBLK);

    // ---- init state in registers ----
    {
        unsigned key = __hip_atomic_load(&sync[1], __ATOMIC_RELAXED,
                                         __HIP_MEMORY_SCOPE_AGENT);
        unsigned u = (key & 0x80000000u) ? (key ^ 0x80000000u) : ~key;
        float gmax = __uint_as_float(u);
        float inv_denom = 1.f / (gmax*1.01f + 1.f);   // one-time, IEEE div
        if (act) {
#pragma unroll
            for (int k = 0; k < 4; ++k) {
                st[k] = make_float4(yv4[k], 1.f,
                                    k1[k].z*inv_denom, k1[k].w*inv_denom);
                v[k]  = make_float4(0.f, 0.f, 0.f, 0.f);
            }
        }
    }

    // ---- 10 phases of T=10 fused Jacobi iterations ----
    unsigned int barno = 2;
#pragma unroll 1
    for (int p = 0; p < NPH; ++p) {
        if (act) {
#pragma unroll
            for (int k = 0; k < 4; ++k)
                buf[0][(4*rg + k)*TS + col] = st[k];
        }
        __syncthreads();

        // r8 inner loop (known-best): dbuf LDS, 1 barrier/iter
#pragma unroll 1
        for (int s = 0; s < T; ++s) {
            const float4* __restrict__ cur = buf[s & 1];
            float4*       __restrict__ nxt = buf[(s & 1) ^ 1];
            if (act) {
                int r0 = 4*rg;
                float4 ns[4];
                float4 up0 = cur[((rg == 0) ? 0 : (r0-1))*TS + col];
                float4 dn3 = cur[((rg == NRG-1) ? (TILE-1) : (r0+4))*TS + col];
#pragma unroll
                for (int k = 0; k < 4; ++k) {
                    int r = r0 + k;
                    float4 lf = cur[r*TS + cl];
                    float4 rt = cur[r*TS + cr];
                    float4 up = (k == 0) ? up0 : st[k-1];
                    float4 dn = (k == 3) ? dn3 : st[k+1];
                    float4 S  = st[k];
                    float4 K  = k1[k];
                    float2 K2 = k2[k];
                    float dmu = K.x*S.x + K.y + K.z*dn.x + K.w*rt.x
                              + K2.x*up.x + K2.y*lf.x;
                    float dsg = K.x*S.y + K.z*S.z*dn.y + K.w*S.w*rt.y
                              + K2.x*up.z*up.y + K2.y*lf.w*lf.y;
                    float dr0 = K.z*S.y*dn.y;
                    float dr1 = K.w*S.y*rt.y;
                    float4 V = v[k];
                    V.x = 0.7f*V.x + 0.01f*dmu;
                    V.y = 0.7f*V.y + 0.01f*dsg;
                    V.z = 0.7f*V.z + 0.01f*dr0;
                    V.w = 0.7f*V.w + 0.01f*dr1;
                    v[k] = V;
                    float4 o;
                    o.x = clampf(S.x + V.x, 0.f, 63.f);
                    o.y = clampf(S.y + V.y, 0.001f, 50.f);
                    o.z = clampf(S.z + V.z, -0.99f, 0.99f);
                    o.w = clampf(S.w + V.w, -0.99f, 0.99f);
                    ns[k] = o;
                }
#pragma unroll
                for (int k = 0; k < 4; ++k) {
                    st[k] = ns[k];
                    nxt[(4*rg + k)*TS + col] = ns[k];
                }
            }
            __syncthreads();
        }

        if (p < NPH-1) {
            // publish interior, grid barrier, refresh halo
            if (act) {
#pragma unroll
                for (int k = 0; k < 4; ++k) {
                    if (inter[k]) {
                        stP[gidx[k]] = st[k];
                        vP[gidx[k]]  = v[k];
                    }
                }
            }
            gbar(&sync[0], barno * NBLK);
            ++barno;
            if (act) {
#pragma unroll
                for (int k = 0; k < 4; ++k) {
                    if (!inter[k]) {
                        st[k] = stP[gidx[k]];
                        v[k]  = vP[gidx[k]];
                    }
                }
            }
        } else {
            // final phase: interior mu -> output
            if (act) {
#pragma unroll
                for (int k = 0; k < 4; ++k)
                    if (inter[k]) out[gidx[k]] = st[k].x;
            }
        }
    }
}

extern "C" void kernel_launch(void* const* d_in, const int* in_sizes, int n_in,
                              void* d_out, int out_size, void* d_ws, size_t ws_size,
                              hipStream_t stream) {
    const float*  y  = (const float*)d_in[0];
    const float2* ew = (const float2*)d_in[1];
    const float2* uw = (const float2*)d_in[2];
    float* out = (float*)d_out;

    // workspace: stP, vP (float4 planes, 8.4 MB) + sync[2]
    float4* stP = (float4*)d_ws;
    float4* vP  = stP + NPIX;
    unsigned int* sync = (unsigned int*)(vP + NPIX);

    hipMemsetAsync(sync, 0, 2*sizeof(unsigned int), stream);
    hipLaunchKernelGGL(osi_persist, dim3(8, 8, 4), dim3(1024), 0, stream,
                       y, ew, uw, sync, stP, vP, out);
}

// Round 12
// 412.893 us; speedup vs baseline: 4.8739x; 1.1882x over previous
//
#include <hip/hip_runtime.h>
#include <math.h>

// B=4, H=256, W=256, 100 iters. Closed-form update (3-pt GH quadrature is
// exact for these degree<=4 integrands; log/NDC terms cancel):
//   dmu  = 2*uw1*mu + uw2*y + sum_edges ew*mu_nb
//   dsg  = 2*uw1*sg + sum_edges ew*rou_edge*sg_nb
//   drou = ew*sg_self*sg_nb        (per owned edge)
// ONE persistent kernel, 10 phases of T=10 temporally-blocked Jacobi
// iterations (52x52 halo tile -> 32x32 interior, r8 inner loop), separated
// by a hand-rolled grid barrier.
// Round 12 (r11 post-mortem): r11 still wrote 97 MB to HBM — each phase's
// 256 RELEASE RMWs emit buffer_wbl2, force-writing the dirty exchange set
// to HBM (~24 us/phase). Fix: move the DATA to the coherence point instead
// of flushing caches. All st/v exchange uses __hip_atomic_{store,load}
// (RELAXED, SCOPE_AGENT) 8-byte ops -> sc1 accesses that hit the LLC
// directly, bypassing the non-coherent per-XCD L2s. Barrier: __syncthreads
// drains vmcnt(0) (sc1 stores at LLC before arrival), RELAXED fetch_add
// arrival, RELAXED spin, NO fences => zero wbl2/inv instructions in the
// whole kernel. Halo loads can't be stale (every one is an LLC access);
// in-order wave issue + s_barrier orders them after spin exit.
#define NPIX  262144
#define ITERS 100
#define T     10
#define NPH   10           // ITERS / T
#define TILE  52           // 32 + 2*T
#define TS    53           // padded LDS row stride (float4 units) — r8 fix
#define NRG   13           // rowgroups of 4 rows: 13*4 = 52 exact
#define ACTIVE (TILE*NRG)  // 676 active threads of 1024
#define NBLK  256

typedef unsigned long long u64;

__device__ __forceinline__ float clampf(float x, float lo, float hi) {
    return fminf(fmaxf(x, lo), hi);
}

// 8-byte LLC-resident (sc1) exchange primitives
__device__ __forceinline__ void stash8(u64* p, float a, float b) {
    union { float f[2]; u64 u; } x;
    x.f[0] = a; x.f[1] = b;
    __hip_atomic_store(p, x.u, __ATOMIC_RELAXED, __HIP_MEMORY_SCOPE_AGENT);
}
__device__ __forceinline__ float2 fetch8(const u64* p) {
    union { u64 u; float f[2]; } x;
    x.u = __hip_atomic_load((u64*)p, __ATOMIC_RELAXED, __HIP_MEMORY_SCOPE_AGENT);
    return make_float2(x.f[0], x.f[1]);
}

// grid barrier: monotone counter, one arrival per block, ZERO fences.
__device__ __forceinline__ void gbar(unsigned int* ctr, unsigned int target) {
    __syncthreads();   // vmcnt(0): all sc1 stores retired at LLC
    if (threadIdx.x == 0) {
        __hip_atomic_fetch_add(ctr, 1u, __ATOMIC_RELAXED,
                               __HIP_MEMORY_SCOPE_AGENT);
        while (__hip_atomic_load(ctr, __ATOMIC_RELAXED,
                                 __HIP_MEMORY_SCOPE_AGENT) < target)
            __builtin_amdgcn_s_sleep(2);
    }
    __syncthreads();
    asm volatile("" ::: "memory");   // compiler barrier only
}

// State float4 {mu, sigma, rou0(down-edge), rou1(right-edge)}.
__global__ __launch_bounds__(1024, 4) void osi_persist(
    const float*  __restrict__ y,
    const float2* __restrict__ ew,
    const float2* __restrict__ uw,
    unsigned int* __restrict__ sync,   // [0]=barrier ctr, [1]=gmax enc; memset 0
    u64* __restrict__ stU,             // 2 u64 per px {mu,sg},{r0,r1}
    u64* __restrict__ vU,              // 2 u64 per px
    float* __restrict__ out)
{
    __shared__ float4 buf[2][TILE*TS];   // 88.3 KB -> 1 block/CU

    int tid = threadIdx.x;
    int rg  = tid / TILE;
    int col = tid - rg*TILE;
    bool act = (tid < ACTIVE);
    int bz = blockIdx.z;
    int h0 = blockIdx.y * 32;
    int w0 = blockIdx.x * 32;
    int w  = (w0 + col - T) & 255;
    bool cin = (col >= T) && (col < T+32);

    float4 st[4], v[4], k1[4];
    float2 k2[4];
    int    gidx[4];
    float  yv4[4];
    bool   inter[4];

    // ---- one-time load of invariants ----
    float m = -INFINITY;
    if (act) {
#pragma unroll
        for (int k = 0; k < 4; ++k) {
            int r = 4*rg + k;
            int h = (h0 + r - T) & 255;
            int g = (bz << 16) | (h << 8) | w;
            gidx[k] = g;
            float2 e = ew[g];
            float2 u = uw[g];
            float yv = y[g];
            yv4[k] = yv;
            k1[k] = make_float4(2.f*u.x, u.y*yv, e.x, e.y);
            m = fmaxf(m, fmaxf(e.x, e.y));
            inter[k] = cin && (r >= T) && (r < T+32);
        }
    }
    // one-time k2 derivation via LDS staging (buf[1], overwritten by iter 0)
    float2* ews = (float2*)&buf[1][0];
    if (act) {
#pragma unroll
        for (int k = 0; k < 4; ++k)
            ews[(4*rg + k)*TS + col] = make_float2(k1[k].z, k1[k].w);
    }
    __syncthreads();
    int cl = (col == 0)      ? 0      : col-1;
    int cr = (col == TILE-1) ? TILE-1 : col+1;
    if (act) {
#pragma unroll
        for (int k = 0; k < 4; ++k) {
            int r  = 4*rg + k;
            int ru = (r == 0) ? 0 : r-1;
            k2[k] = make_float2(ews[ru*TS + col].x, ews[r*TS + cl].y);
        }
    }

    // ---- global max(ew) (barrier #1) ----
#pragma unroll
    for (int off = 32; off > 0; off >>= 1)
        m = fmaxf(m, __shfl_down(m, off, 64));
    if ((tid & 63) == 0) {
        unsigned u = __float_as_uint(m);
        unsigned key = (u & 0x80000000u) ? ~u : (u | 0x80000000u);
        atomicMax(&sync[1], key);
    }
    gbar(&sync[0], NBLK);

    // ---- init state in registers ----
    {
        unsigned key = __hip_atomic_load(&sync[1], __ATOMIC_RELAXED,
                                         __HIP_MEMORY_SCOPE_AGENT);
        unsigned u = (key & 0x80000000u) ? (key ^ 0x80000000u) : ~key;
        float gmax = __uint_as_float(u);
        float inv_denom = 1.f / (gmax*1.01f + 1.f);   // one-time, IEEE div
        if (act) {
#pragma unroll
            for (int k = 0; k < 4; ++k) {
                st[k] = make_float4(yv4[k], 1.f,
                                    k1[k].z*inv_denom, k1[k].w*inv_denom);
                v[k]  = make_float4(0.f, 0.f, 0.f, 0.f);
            }
        }
    }

    // ---- 10 phases of T=10 fused Jacobi iterations ----
    unsigned int barno = 2;
#pragma unroll 1
    for (int p = 0; p < NPH; ++p) {
        if (act) {
#pragma unroll
            for (int k = 0; k < 4; ++k)
                buf[0][(4*rg + k)*TS + col] = st[k];
        }
        __syncthreads();

        // r8 inner loop (known-best): dbuf LDS, 1 barrier/iter
#pragma unroll 1
        for (int s = 0; s < T; ++s) {
            const float4* __restrict__ cur = buf[s & 1];
            float4*       __restrict__ nxt = buf[(s & 1) ^ 1];
            if (act) {
                int r0 = 4*rg;
                float4 ns[4];
                float4 up0 = cur[((rg == 0) ? 0 : (r0-1))*TS + col];
                float4 dn3 = cur[((rg == NRG-1) ? (TILE-1) : (r0+4))*TS + col];
#pragma unroll
                for (int k = 0; k < 4; ++k) {
                    int r = r0 + k;
                    float4 lf = cur[r*TS + cl];
                    float4 rt = cur[r*TS + cr];
                    float4 up = (k == 0) ? up0 : st[k-1];
                    float4 dn = (k == 3) ? dn3 : st[k+1];
                    float4 S  = st[k];
                    float4 K  = k1[k];
                    float2 K2 = k2[k];
                    float dmu = K.x*S.x + K.y + K.z*dn.x + K.w*rt.x
                              + K2.x*up.x + K2.y*lf.x;
                    float dsg = K.x*S.y + K.z*S.z*dn.y + K.w*S.w*rt.y
                              + K2.x*up.z*up.y + K2.y*lf.w*lf.y;
                    float dr0 = K.z*S.y*dn.y;
                    float dr1 = K.w*S.y*rt.y;
                    float4 V = v[k];
                    V.x = 0.7f*V.x + 0.01f*dmu;
                    V.y = 0.7f*V.y + 0.01f*dsg;
                    V.z = 0.7f*V.z + 0.01f*dr0;
                    V.w = 0.7f*V.w + 0.01f*dr1;
                    v[k] = V;
                    float4 o;
                    o.x = clampf(S.x + V.x, 0.f, 63.f);
                    o.y = clampf(S.y + V.y, 0.001f, 50.f);
                    o.z = clampf(S.z + V.z, -0.99f, 0.99f);
                    o.w = clampf(S.w + V.w, -0.99f, 0.99f);
                    ns[k] = o;
                }
#pragma unroll
                for (int k = 0; k < 4; ++k) {
                    st[k] = ns[k];
                    nxt[(4*rg + k)*TS + col] = ns[k];
                }
            }
            __syncthreads();
        }

        if (p < NPH-1) {
            // publish interior (sc1 -> LLC), grid barrier, refresh halo (sc1)
            if (act) {
#pragma unroll
                for (int k = 0; k < 4; ++k) {
                    if (inter[k]) {
                        int g = gidx[k];
                        stash8(&stU[2*g    ], st[k].x, st[k].y);
                        stash8(&stU[2*g + 1], st[k].z, st[k].w);
                        stash8(&vU [2*g    ], v[k].x,  v[k].y);
                        stash8(&vU [2*g + 1], v[k].z,  v[k].w);
                    }
                }
            }
            gbar(&sync[0], barno * NBLK);
            ++barno;
            if (act) {
#pragma unroll
                for (int k = 0; k < 4; ++k) {
                    if (!inter[k]) {
                        int g = gidx[k];
                        float2 a = fetch8(&stU[2*g    ]);
                        float2 b = fetch8(&stU[2*g + 1]);
                        float2 c = fetch8(&vU [2*g    ]);
                        float2 d = fetch8(&vU [2*g + 1]);
                        st[k] = make_float4(a.x, a.y, b.x, b.y);
                        v[k]  = make_float4(c.x, c.y, d.x, d.y);
                    }
                }
            }
        } else {
            // final phase: interior mu -> output (plain stores; kernel end flushes)
            if (act) {
#pragma unroll
                for (int k = 0; k < 4; ++k)
                    if (inter[k]) out[gidx[k]] = st[k].x;
            }
        }
    }
}

extern "C" void kernel_launch(void* const* d_in, const int* in_sizes, int n_in,
                              void* d_out, int out_size, void* d_ws, size_t ws_size,
                              hipStream_t stream) {
    const float*  y  = (const float*)d_in[0];
    const float2* ew = (const float2*)d_in[1];
    const float2* uw = (const float2*)d_in[2];
    float* out = (float*)d_out;

    // workspace: stU, vU (2 u64/px = 4.2 MB each) + sync[2]
    u64* stU = (u64*)d_ws;
    u64* vU  = stU + 2*NPIX;
    unsigned int* sync = (unsigned int*)(vU + 2*NPIX);

    hipMemsetAsync(sync, 0, 2*sizeof(unsigned int), stream);
    hipLaunchKernelGGL(osi_persist, dim3(8, 8, 4), dim3(1024), 0, stream,
                       y, ew, uw, sync, stU, vU, out);
}